// Round 7
// baseline (209.875 us; speedup 1.0000x reference)
//
#include <hip/hip_runtime.h>
#include <hip/hip_fp16.h>
#include <cstddef>

#define N_ 1024
#define M_ 1024
#define D_ 1024
#define G_ 16
#define DG_ 64

typedef __bf16 bf16x8 __attribute__((ext_vector_type(8)));
typedef _Float16 f16x8 __attribute__((ext_vector_type(8)));
typedef float f32x4 __attribute__((ext_vector_type(4)));

// ---------------------------------------------------------------------------
// Prep: z=0/1 transpose-cast Wq/Wk -> [go][d] bf16; z=2 cast Wv; z=3 cast roi;
// z=4 cast ref. 64x64 tiles.
// ---------------------------------------------------------------------------
__global__ __launch_bounds__(256)
void prep_weights(const float* __restrict__ Wq, const float* __restrict__ Wk,
                  const float* __restrict__ Wv, const float* __restrict__ roi,
                  const float* __restrict__ ref,
                  __bf16* __restrict__ WqT, __bf16* __restrict__ WkT,
                  __bf16* __restrict__ Wvb, __bf16* __restrict__ roibf,
                  __bf16* __restrict__ refbf)
{
    const int z = blockIdx.z;
    const int i0 = blockIdx.x * 64, j0 = blockIdx.y * 64;
    const int tid = threadIdx.x;
    const int r = tid >> 4, c4 = (tid & 15) * 4;

    if (z >= 2) {
        const float* src = (z == 2) ? Wv : (z == 3) ? roi : ref;
        __bf16* dst = (z == 2) ? Wvb : (z == 3) ? roibf : refbf;
        #pragma unroll
        for (int it = 0; it < 4; ++it) {
            const int row = r + it * 16;
            float4 a = *(const float4*)&src[(size_t)(i0 + row) * D_ + j0 + c4];
            __bf16 p[4] = {(__bf16)a.x, (__bf16)a.y, (__bf16)a.z, (__bf16)a.w};
            *(uint2*)&dst[(size_t)(i0 + row) * D_ + j0 + c4] = *(const uint2*)p;
        }
        return;
    }

    __shared__ float t[64][65];
    const float* src = z ? Wk : Wq;
    __bf16* dst = z ? WkT : WqT;
    #pragma unroll
    for (int it = 0; it < 4; ++it) {
        float4 a = *(const float4*)&src[(size_t)(i0 + r + it * 16) * D_ + j0 + c4];
        t[r + it * 16][c4 + 0] = a.x; t[r + it * 16][c4 + 1] = a.y;
        t[r + it * 16][c4 + 2] = a.z; t[r + it * 16][c4 + 3] = a.w;
    }
    __syncthreads();
    #pragma unroll
    for (int it = 0; it < 4; ++it) {
        const int row = r + it * 16;
        __bf16 p[4];
        #pragma unroll
        for (int q = 0; q < 4; ++q) p[q] = (__bf16)t[c4 + q][row];
        *(uint2*)&dst[(size_t)(j0 + row) * D_ + i0 + c4] = *(const uint2*)p;
    }
}

// ---------------------------------------------------------------------------
// Split-K MFMA GEMM: grid (8,8,12) = 3 z * 4 K-splits, 128x128 tile, BK=64,
// 4 k-iters per block. Writes bf16 partials (no bias) via LDS-staged epilogue.
// ---------------------------------------------------------------------------
#define GP 72

__global__ __launch_bounds__(256, 2)
void gemm_mfma(const __bf16* __restrict__ roibf, const __bf16* __restrict__ refbf,
               const __bf16* __restrict__ WqT, const __bf16* __restrict__ WkT,
               const __bf16* __restrict__ Wvb, __bf16* __restrict__ part)
{
    __shared__ __align__(16) char smem[36864];   // As 128x72 + Bs 128x72 bf16

    const int zs = blockIdx.z, z = zs >> 2, s = zs & 3;
    const __bf16* A = (z == 0) ? roibf : refbf;
    const __bf16* B = (z == 0) ? WqT : (z == 1) ? WkT : Wvb;
    __bf16* dst = part + ((size_t)zs << 20);

    const int tid = threadIdx.x;
    const int i0 = blockIdx.x * 128, j0 = blockIdx.y * 128;
    const int w = tid >> 6, lane = tid & 63;
    const int quad = lane >> 4, l15 = lane & 15;
    const int iw = (w & 1) * 64, jw = (w >> 1) * 64;

    __bf16(*As)[GP] = (__bf16(*)[GP])smem;
    __bf16(*Bs)[GP] = (__bf16(*)[GP])(smem + 18432);

    const int srow = tid >> 3, sc = (tid & 7) * 8;

    f32x4 acc[4][4] = {};
    uint4 ra[4], rb[4];

    auto load_tile = [&](int kt) {
        const int k0 = s * 256 + kt * 64;
        #pragma unroll
        for (int it = 0; it < 4; ++it)
            ra[it] = *(const uint4*)&A[(size_t)(i0 + srow + it * 32) * D_ + k0 + sc];
        #pragma unroll
        for (int it = 0; it < 4; ++it)
            rb[it] = *(const uint4*)&B[(size_t)(j0 + srow + it * 32) * D_ + k0 + sc];
    };
    auto write_tile = [&]() {
        #pragma unroll
        for (int it = 0; it < 4; ++it)
            *(uint4*)&As[srow + it * 32][sc] = ra[it];
        #pragma unroll
        for (int it = 0; it < 4; ++it)
            *(uint4*)&Bs[srow + it * 32][sc] = rb[it];
    };

    load_tile(0);
    write_tile();
    __syncthreads();

    for (int kt = 0; kt < 4; ++kt) {
        if (kt < 3) load_tile(kt + 1);

        #pragma unroll
        for (int ks = 0; ks < 2; ++ks) {
            bf16x8 af[4], bfr[4];
            #pragma unroll
            for (int t = 0; t < 4; ++t) {
                af[t]  = *(const bf16x8*)&As[iw + t * 16 + l15][ks * 32 + quad * 8];
                bfr[t] = *(const bf16x8*)&Bs[jw + t * 16 + l15][ks * 32 + quad * 8];
            }
            #pragma unroll
            for (int ti = 0; ti < 4; ++ti)
                #pragma unroll
                for (int tj = 0; tj < 4; ++tj)
                    acc[ti][tj] = __builtin_amdgcn_mfma_f32_16x16x32_bf16(
                        af[ti], bfr[tj], acc[ti][tj], 0, 0, 0);
        }
        __syncthreads();
        if (kt < 3) {
            write_tile();
            __syncthreads();
        }
    }

    // epilogue: stage bf16 partial tile in LDS, coalesced row copy out
    __bf16(*Ct)[136] = (__bf16(*)[136])smem;   // 128 x 136 = 34816 B
    #pragma unroll
    for (int ti = 0; ti < 4; ++ti)
        #pragma unroll
        for (int tj = 0; tj < 4; ++tj) {
            const int col = jw + tj * 16 + l15;
            #pragma unroll
            for (int r = 0; r < 4; ++r)
                Ct[iw + ti * 16 + quad * 4 + r][col] = (__bf16)acc[ti][tj][r];
        }
    __syncthreads();
    const int orow = tid >> 1, oh = (tid & 1) * 64;
    __bf16* gp = dst + (size_t)(i0 + orow) * 1024 + j0 + oh;
    #pragma unroll
    for (int c = 0; c < 8; ++c)
        *(uint4*)&gp[c * 8] = *(const uint4*)&Ct[orow][oh + c * 8];
}

// ---------------------------------------------------------------------------
// Reduce 4 split-K partials + bias/scale/cast; z=2 also transposes to Vt.
// Grid: 768 linear blocks (z = b>>8, 64x64 tile = b&255).
// ---------------------------------------------------------------------------
__global__ __launch_bounds__(256)
void reduce_eps(const __bf16* __restrict__ part, const float* __restrict__ bq,
                const float* __restrict__ bk, __bf16* __restrict__ qout,
                __bf16* __restrict__ kout, __bf16* __restrict__ Vt)
{
    const int b = blockIdx.x;
    const int z = b >> 8, tile = b & 255;
    const int i0 = (tile >> 4) * 64, j0 = (tile & 15) * 64;
    const __bf16* P = part + ((size_t)(z * 4) << 20);
    const int t = threadIdx.x;
    const int r = t >> 2, c0 = (t & 3) * 16;

    float sum[16] = {};
    #pragma unroll
    for (int s = 0; s < 4; ++s) {
        const __bf16* bp = P + ((size_t)s << 20) + (size_t)(i0 + r) * 1024 + j0 + c0;
        bf16x8 v0 = *(const bf16x8*)bp;
        bf16x8 v1 = *(const bf16x8*)(bp + 8);
        #pragma unroll
        for (int e = 0; e < 8; ++e) { sum[e] += (float)v0[e]; sum[8 + e] += (float)v1[e]; }
    }

    if (z < 2) {
        const float* bias = z ? bk : bq;
        const float scale = z ? 1.0f : 0.125f;
        __bf16 o[16];
        #pragma unroll
        for (int e = 0; e < 16; ++e)
            o[e] = (__bf16)((sum[e] + bias[j0 + c0 + e]) * scale);
        __bf16* out = z ? kout : qout;
        __bf16* gp = out + (size_t)(i0 + r) * 1024 + j0 + c0;
        *(uint4*)&gp[0] = *(const uint4*)&o[0];
        *(uint4*)&gp[8] = *(const uint4*)&o[8];
    } else {
        __shared__ float tt[64][65];
        #pragma unroll
        for (int e = 0; e < 16; ++e) tt[r][c0 + e] = sum[e];
        __syncthreads();
        const int gor = t >> 2, m0c = (t & 3) * 16;
        __bf16 o[16];
        #pragma unroll
        for (int e = 0; e < 16; ++e) o[e] = (__bf16)tt[m0c + e][gor];
        __bf16* gp = Vt + (size_t)(j0 + gor) * M_ + i0 + m0c;
        *(uint4*)&gp[0] = *(const uint4*)&o[0];
        *(uint4*)&gp[8] = *(const uint4*)&o[8];
    }
}

// ---------------------------------------------------------------------------
// Positional affinity via MFMA f16 -> aw[g][n][m] fp16.
// ---------------------------------------------------------------------------
__global__ __launch_bounds__(256)
void posbias_mfma(const float* __restrict__ rois1, const float* __restrict__ rois2,
                  const float* __restrict__ Wg, const float* __restrict__ bg,
                  __half* __restrict__ aw)
{
    __shared__ __half pt[4][16][72];

    const int tid = threadIdx.x;
    const int w = tid >> 6, lane = tid & 63;
    const int quad = lane >> 4, l15 = lane & 15;
    const int n = blockIdx.y;
    const int m0w = blockIdx.x * 256 + w * 64;

    const float xmin = rois1[n * 4 + 0], ymin = rois1[n * 4 + 1];
    const float xmax = rois1[n * 4 + 2], ymax = rois1[n * 4 + 3];
    const float wn  = xmax - xmin + 1.f, hn  = ymax - ymin + 1.f;
    const float cxn = 0.5f * (xmin + xmax), cyn = 0.5f * (ymin + ymax);

    f16x8 wgf[2];
    #pragma unroll
    for (int ks = 0; ks < 2; ++ks) {
        const float* p = &Wg[l15 * 64 + ks * 32 + quad * 8];
        float4 a = *(const float4*)p;
        float4 b = *(const float4*)(p + 4);
        wgf[ks][0] = (_Float16)a.x; wgf[ks][1] = (_Float16)a.y;
        wgf[ks][2] = (_Float16)a.z; wgf[ks][3] = (_Float16)a.w;
        wgf[ks][4] = (_Float16)b.x; wgf[ks][5] = (_Float16)b.y;
        wgf[ks][6] = (_Float16)b.z; wgf[ks][7] = (_Float16)b.w;
    }
    const float bgv = bg[l15];

    const float fr8[8] = {100.0f, 42.16965f, 17.782794f, 7.4989421f,
                          3.1622777f, 1.3335214f, 0.56234133f, 0.23713737f};
    const float phase = (quad & 1) ? 1.5707963267948966f : 0.f;

    #pragma unroll
    for (int ti = 0; ti < 4; ++ti) {
        const int mt0 = m0w + ti * 16;
        const int m = mt0 + l15;
        float4 r2 = *(const float4*)&rois2[m * 4];
        const float wr  = r2.z - r2.x + 1.f, hr  = r2.w - r2.y + 1.f;
        const float cxr = 0.5f * (r2.x + r2.z), cyr = 0.5f * (r2.y + r2.w);

        const float f0 = __logf(fabsf((cxn - cxr) / wn) + 0.001f);
        const float f1 = __logf(fabsf((cyn - cyr) / hn) + 0.001f);
        const float f2 = __logf(wn / wr);
        const float f3 = __logf(hn / hr);
        const float fa = (quad & 2) ? f1 : f0;
        const float fb = (quad & 2) ? f3 : f2;

        f32x4 acc = {};
        #pragma unroll
        for (int ks = 0; ks < 2; ++ks) {
            const float feat = ks ? fb : fa;
            f16x8 ef;
            #pragma unroll
            for (int j = 0; j < 8; ++j)
                ef[j] = (_Float16)__sinf(fmaf(feat, fr8[j], phase));
            acc = __builtin_amdgcn_mfma_f32_16x16x32_f16(ef, wgf[ks], acc, 0, 0, 0);
        }

        __half p[4];
        #pragma unroll
        for (int r = 0; r < 4; ++r)
            p[r] = __float2half(fmaxf(acc[r] + bgv, 0.f) + 1e-6f);
        *(uint2*)&pt[w][l15][ti * 16 + quad * 4] = *(const uint2*)p;
    }

    const int gg = lane >> 2, mseg = (lane & 3) * 16;
    __half* dst = aw + (size_t)gg * N_ * M_ + (size_t)n * M_ + m0w + mseg;
    *(uint4*)&dst[0] = *(const uint4*)&pt[w][gg][mseg];
    *(uint4*)&dst[8] = *(const uint4*)&pt[w][gg][mseg + 8];
}

// ---------------------------------------------------------------------------
// Wave-autonomous MFMA attention. Linear grid 1024: g = b&15 (XCD affinity),
// nb = b>>4. Each wave owns a 256-m chunk; LDS combine at end.
// ---------------------------------------------------------------------------
__global__ __launch_bounds__(256)
void attn_mfma(const __bf16* __restrict__ qb, const __bf16* __restrict__ kb,
               const __bf16* __restrict__ Vt, const __half* __restrict__ aw,
               const float* __restrict__ bv, float* __restrict__ out)
{
    __shared__ __bf16 Ps[4][2][16][72];
    __shared__ float accb[4][64][17];
    __shared__ float lsb[4][16];

    const int tid = threadIdx.x;
    const int w = tid >> 6, lane = tid & 63;
    const int quad = lane >> 4, l15 = lane & 15;
    const int b = blockIdx.x;
    const int g = b & 15, nb = b >> 4, n0 = nb * 16;

    bf16x8 qf[2];
    qf[0] = *(const bf16x8*)&qb[(size_t)(n0 + l15) * D_ + g * 64 + quad * 8];
    qf[1] = *(const bf16x8*)&qb[(size_t)(n0 + l15) * D_ + g * 64 + 32 + quad * 8];

    f32x4 acc[4] = {};
    float llocal = 0.f;

    #pragma unroll
    for (int t64 = 0; t64 < 4; ++t64) {
        const int mt = w * 4 + t64;
        const int m0 = mt * 64;
        const int buf = t64 & 1;

        f32x4 s[4];
        #pragma unroll
        for (int t = 0; t < 4; ++t) {
            const __bf16* kr = &kb[(size_t)(m0 + t * 16 + l15) * D_ + g * 64 + quad * 8];
            bf16x8 ka0 = *(const bf16x8*)kr;
            bf16x8 ka1 = *(const bf16x8*)(kr + 32);
            f32x4 zz = {};
            zz = __builtin_amdgcn_mfma_f32_16x16x32_bf16(ka0, qf[0], zz, 0, 0, 0);
            s[t] = __builtin_amdgcn_mfma_f32_16x16x32_bf16(ka1, qf[1], zz, 0, 0, 0);
        }

        #pragma unroll
        for (int t = 0; t < 4; ++t) {
            uint2 au = *(const uint2*)&aw[((size_t)g * N_ + n0 + l15) * M_ +
                                          m0 + t * 16 + quad * 4];
            const __half* a4 = (const __half*)&au;
            __bf16 pk[4];
            #pragma unroll
            for (int r = 0; r < 4; ++r) {
                const float p = __half2float(a4[r]) * __expf(s[t][r]);
                llocal += p;
                pk[r] = (__bf16)p;
            }
            *(uint2*)&Ps[w][buf][l15][t * 16 + quad * 4] = *(const uint2*)pk;
        }

        #pragma unroll
        for (int mcl = 0; mcl < 2; ++mcl) {
            bf16x8 pb = *(const bf16x8*)&Ps[w][buf][l15][mcl * 32 + quad * 8];
            #pragma unroll
            for (int ot = 0; ot < 4; ++ot) {
                bf16x8 va = *(const bf16x8*)&Vt[(size_t)(g * 64 + ot * 16 + l15) * M_ +
                                                m0 + mcl * 32 + quad * 8];
                acc[ot] = __builtin_amdgcn_mfma_f32_16x16x32_bf16(va, pb, acc[ot], 0, 0, 0);
            }
        }
    }

    llocal += __shfl_xor(llocal, 16, 64);
    llocal += __shfl_xor(llocal, 32, 64);

    #pragma unroll
    for (int ot = 0; ot < 4; ++ot)
        #pragma unroll
        for (int r = 0; r < 4; ++r)
            accb[w][ot * 16 + quad * 4 + r][l15] = acc[ot][r];
    if (quad == 0) lsb[w][l15] = llocal;
    __syncthreads();

    const float lt = lsb[0][l15] + lsb[1][l15] + lsb[2][l15] + lsb[3][l15];
    const float inv = 1.f / lt;
    #pragma unroll
    for (int r = 0; r < 4; ++r) {
        const int o = w * 16 + quad * 4 + r;
        const int ogl = g * 64 + o;
        const float v = accb[0][o][l15] + accb[1][o][l15] +
                        accb[2][o][l15] + accb[3][o][l15];
        out[(size_t)(n0 + l15) * D_ + ogl] = v * inv + bv[ogl];
    }
}

extern "C" void kernel_launch(void* const* d_in, const int* in_sizes, int n_in,
                              void* d_out, int out_size, void* d_ws, size_t ws_size,
                              hipStream_t stream) {
    const float* roi_feat = (const float*)d_in[0];
    const float* ref_feat = (const float*)d_in[1];
    const float* rois1    = (const float*)d_in[2];
    const float* rois2    = (const float*)d_in[3];
    const float* Wq       = (const float*)d_in[4];
    const float* bq       = (const float*)d_in[5];
    const float* Wk       = (const float*)d_in[6];
    const float* bk       = (const float*)d_in[7];
    const float* Wg       = (const float*)d_in[8];
    const float* bg       = (const float*)d_in[9];
    const float* Wv       = (const float*)d_in[10];
    const float* bv       = (const float*)d_in[11];
    float* out = (float*)d_out;

    // ws (bytes): WqT 0-2M | WkT 2-4M | Wvb 4-6M | q 6-8M | k 8-10M | Vt 10-12M
    //             aw 12-44M | roibf 44-46M | refbf 46-48M | partials 48-72M
    char* ws = (char*)d_ws;
    __bf16* WqT   = (__bf16*)(ws + 0);
    __bf16* WkT   = (__bf16*)(ws + (2u << 20));
    __bf16* Wvb   = (__bf16*)(ws + (4u << 20));
    __bf16* qbuf  = (__bf16*)(ws + (6u << 20));
    __bf16* kbuf  = (__bf16*)(ws + (8u << 20));
    __bf16* Vtb   = (__bf16*)(ws + (10u << 20));
    __half* aw    = (__half*)(ws + (12u << 20));
    __bf16* roibf = (__bf16*)(ws + (44u << 20));
    __bf16* refbf = (__bf16*)(ws + (46u << 20));
    __bf16* part  = (__bf16*)(ws + (48u << 20));

    dim3 blk(256);
    prep_weights<<<dim3(16, 16, 5), blk, 0, stream>>>(Wq, Wk, Wv, roi_feat, ref_feat,
                                                      WqT, WkT, Wvb, roibf, refbf);
    posbias_mfma<<<dim3(4, 1024), blk, 0, stream>>>(rois1, rois2, Wg, bg, aw);
    gemm_mfma<<<dim3(8, 8, 12), blk, 0, stream>>>(roibf, refbf, WqT, WkT, Wvb, part);
    reduce_eps<<<dim3(768), blk, 0, stream>>>(part, bq, bk, qbuf, kbuf, Vtb);
    attn_mfma<<<dim3(1024), blk, 0, stream>>>(qbuf, kbuf, Vtb, aw, bv, out);
}

// Round 9
// 153.505 us; speedup vs baseline: 1.3672x; 1.3672x over previous
//
#include <hip/hip_runtime.h>
#include <hip/hip_fp16.h>
#include <cstddef>

#define N_ 1024
#define M_ 1024
#define D_ 1024
#define G_ 16
#define DG_ 64

typedef __bf16 bf16x8 __attribute__((ext_vector_type(8)));
typedef _Float16 f16x8 __attribute__((ext_vector_type(8)));
typedef float f32x4 __attribute__((ext_vector_type(4)));

// Fragment-major layout helpers (R4, verified passing).
// Qf/Kf: [g][rb(64)][ks(2)][lane(64)][8]
__device__ __forceinline__ size_t qkf_idx(int g, int rb, int ks, int lane) {
    return ((((size_t)(g * 64 + rb)) * 2 + ks) * 64 + lane) * 8;
}
// Vf: [g][ot(4)][mc(32)][lane(64)][8]
__device__ __forceinline__ size_t vf_idx(int g, int ot, int mc, int lane) {
    return ((((size_t)(g * 4 + ot)) * 32 + mc) * 64 + lane) * 8;
}
// AWt: [g][mb(64)][n(1024)][16]
__device__ __forceinline__ size_t awt_idx(int g, int mb, int n, int quad) {
    return (((size_t)(g * 64 + mb)) * 1024 + n) * 16 + quad * 4;
}

// ---------------------------------------------------------------------------
// Prep: z=0/1 transpose-cast Wq/Wk -> [go][d] bf16; z=2 cast Wv (already
// [go][d]) -> bf16. 64x64 tiles, grid (16,16,3).
// ---------------------------------------------------------------------------
__global__ __launch_bounds__(256)
void prep_weights(const float* __restrict__ Wq, const float* __restrict__ Wk,
                  const float* __restrict__ Wv,
                  __bf16* __restrict__ WqT, __bf16* __restrict__ WkT,
                  __bf16* __restrict__ Wvb)
{
    const int z = blockIdx.z;
    const int i0 = blockIdx.x * 64, j0 = blockIdx.y * 64;
    const int tid = threadIdx.x;
    const int r = tid >> 4, c4 = (tid & 15) * 4;

    if (z == 2) {
        #pragma unroll
        for (int it = 0; it < 4; ++it) {
            const int row = r + it * 16;
            float4 a = *(const float4*)&Wv[(size_t)(i0 + row) * D_ + j0 + c4];
            __bf16 p[4] = {(__bf16)a.x, (__bf16)a.y, (__bf16)a.z, (__bf16)a.w};
            *(uint2*)&Wvb[(size_t)(i0 + row) * D_ + j0 + c4] = *(const uint2*)p;
        }
        return;
    }

    __shared__ float t[64][65];
    const float* src = z ? Wk : Wq;
    __bf16* dst = z ? WkT : WqT;
    #pragma unroll
    for (int it = 0; it < 4; ++it) {
        float4 a = *(const float4*)&src[(size_t)(i0 + r + it * 16) * D_ + j0 + c4];
        t[r + it * 16][c4 + 0] = a.x; t[r + it * 16][c4 + 1] = a.y;
        t[r + it * 16][c4 + 2] = a.z; t[r + it * 16][c4 + 3] = a.w;
    }
    __syncthreads();
    #pragma unroll
    for (int it = 0; it < 4; ++it) {
        const int row = r + it * 16;
        __bf16 p[4];
        #pragma unroll
        for (int q = 0; q < 4; ++q) p[q] = (__bf16)t[c4 + q][row];
        *(uint2*)&dst[(size_t)(j0 + row) * D_ + i0 + c4] = *(const uint2*)p;
    }
}

// ---------------------------------------------------------------------------
// Fused mid dispatch: blocks 0..191 run the R4 gemm (128x128 tile, BK=64,
// fragment-major epilogue); blocks 192..4287 run the R4 posbias (MFMA f16,
// AWt fragment layout). Independent work co-scheduled in one dispatch so
// posbias's VALU work fills the latency-bound gemm blocks' idle pipes.
// ---------------------------------------------------------------------------
__global__ __launch_bounds__(256)
void fused_mid(const float* __restrict__ roi, const float* __restrict__ ref,
               const __bf16* __restrict__ WqT, const __bf16* __restrict__ WkT,
               const __bf16* __restrict__ Wvb,
               const float* __restrict__ bq, const float* __restrict__ bk,
               __bf16* __restrict__ Qf, __bf16* __restrict__ Kf,
               __bf16* __restrict__ Vf,
               const float* __restrict__ rois1, const float* __restrict__ rois2,
               const float* __restrict__ Wg, const float* __restrict__ bg,
               __half* __restrict__ AWt)
{
    __shared__ __align__(16) char smem[36864];
    const int b = blockIdx.x;
    const int tid = threadIdx.x;
    const int w = tid >> 6, lane = tid & 63;
    const int quad = lane >> 4, l15 = lane & 15;

    if (b < 192) {
        // ---------------- GEMM branch (R4 verbatim, re-indexed) ----------------
        const int z = b >> 6, t6 = b & 63;
        const float* A = (z == 0) ? roi : ref;
        const __bf16* B = (z == 0) ? WqT : (z == 1) ? WkT : Wvb;
        const int i0 = (t6 >> 3) * 128, j0 = (t6 & 7) * 128;
        const int iw = (w & 1) * 64, jw = (w >> 1) * 64;

        __bf16(*As)[72] = (__bf16(*)[72])smem;
        __bf16(*Bs)[72] = (__bf16(*)[72])(smem + 18432);

        f32x4 acc[4][4] = {};

        for (int k0 = 0; k0 < D_; k0 += 64) {
            __syncthreads();
            #pragma unroll
            for (int it = 0; it < 8; ++it) {
                const int idx = tid + 256 * it;
                const int row = idx >> 4, c = idx & 15;
                float4 a = *(const float4*)&A[(size_t)(i0 + row) * D_ + k0 + c * 4];
                __bf16* d = &As[row][c * 4];
                d[0] = (__bf16)a.x; d[1] = (__bf16)a.y;
                d[2] = (__bf16)a.z; d[3] = (__bf16)a.w;
            }
            #pragma unroll
            for (int it = 0; it < 4; ++it) {
                const int idx = tid + 256 * it;
                const int row = idx >> 3, c = idx & 7;
                *(uint4*)&Bs[row][c * 8] =
                    *(const uint4*)&B[(size_t)(j0 + row) * D_ + k0 + c * 8];
            }
            __syncthreads();
            #pragma unroll
            for (int ks = 0; ks < 2; ++ks) {
                bf16x8 af[4], bfr[4];
                #pragma unroll
                for (int t = 0; t < 4; ++t) {
                    af[t]  = *(const bf16x8*)&As[iw + t * 16 + l15][ks * 32 + quad * 8];
                    bfr[t] = *(const bf16x8*)&Bs[jw + t * 16 + l15][ks * 32 + quad * 8];
                }
                #pragma unroll
                for (int ti = 0; ti < 4; ++ti)
                    #pragma unroll
                    for (int tj = 0; tj < 4; ++tj)
                        acc[ti][tj] = __builtin_amdgcn_mfma_f32_16x16x32_bf16(
                            af[ti], bfr[tj], acc[ti][tj], 0, 0, 0);
            }
        }

        if (z < 2) {
            const float* bias = (z == 0) ? bq : bk;
            __bf16* dst = (z == 0) ? Qf : Kf;
            const float scale = (z == 0) ? 0.125f : 1.0f;
            #pragma unroll
            for (int ti = 0; ti < 4; ++ti) {
                const int rb = (i0 + iw + ti * 16) >> 4;
                #pragma unroll
                for (int tj = 0; tj < 4; ++tj) {
                    const int go = j0 + jw + tj * 16 + l15;
                    const int g = go >> 6, ks = (go >> 5) & 1;
                    const int lanef = ((go >> 3) & 3) * 16;
                    const int jf = go & 7;
                    const float bb = bias[go];
                    __bf16* base = dst + qkf_idx(g, rb, ks, 0) + jf;
                    #pragma unroll
                    for (int r = 0; r < 4; ++r)
                        base[(size_t)(lanef + quad * 4 + r) * 8] =
                            (__bf16)((acc[ti][tj][r] + bb) * scale);
                }
            }
        } else {
            #pragma unroll
            for (int ti = 0; ti < 4; ++ti) {
                const int mbase = i0 + iw + ti * 16 + quad * 4;
                const int mc = mbase >> 5, quadv = (mbase >> 3) & 3, jb = mbase & 7;
                #pragma unroll
                for (int tj = 0; tj < 4; ++tj) {
                    const int go = j0 + jw + tj * 16 + l15;
                    const int g = go >> 6, ot = (go >> 4) & 3, o15 = go & 15;
                    __bf16 p[4];
                    #pragma unroll
                    for (int r = 0; r < 4; ++r) p[r] = (__bf16)acc[ti][tj][r];
                    *(uint2*)&Vf[vf_idx(g, ot, mc, quadv * 16 + o15) + jb] =
                        *(const uint2*)p;
                }
            }
        }
        return;
    }

    // ---------------- posbias branch (R4 verbatim, re-indexed) ----------------
    const int pb = b - 192;
    const int n = pb >> 2;
    const int m0w = (pb & 3) * 256 + w * 64;

    const float xmin = rois1[n * 4 + 0], ymin = rois1[n * 4 + 1];
    const float xmax = rois1[n * 4 + 2], ymax = rois1[n * 4 + 3];
    const float wn  = xmax - xmin + 1.f, hn  = ymax - ymin + 1.f;
    const float cxn = 0.5f * (xmin + xmax), cyn = 0.5f * (ymin + ymax);

    f16x8 wgf[2];
    #pragma unroll
    for (int ks = 0; ks < 2; ++ks) {
        const float* p = &Wg[l15 * 64 + ks * 32 + quad * 8];
        float4 a = *(const float4*)p;
        float4 bb = *(const float4*)(p + 4);
        wgf[ks][0] = (_Float16)a.x; wgf[ks][1] = (_Float16)a.y;
        wgf[ks][2] = (_Float16)a.z; wgf[ks][3] = (_Float16)a.w;
        wgf[ks][4] = (_Float16)bb.x; wgf[ks][5] = (_Float16)bb.y;
        wgf[ks][6] = (_Float16)bb.z; wgf[ks][7] = (_Float16)bb.w;
    }
    const float bgv = bg[l15];

    const float fr8[8] = {100.0f, 42.16965f, 17.782794f, 7.4989421f,
                          3.1622777f, 1.3335214f, 0.56234133f, 0.23713737f};
    const float phase = (quad & 1) ? 1.5707963267948966f : 0.f;

    #pragma unroll
    for (int ti = 0; ti < 4; ++ti) {
        const int mt0 = m0w + ti * 16;
        const int m = mt0 + l15;
        float4 r2 = *(const float4*)&rois2[m * 4];
        const float wr  = r2.z - r2.x + 1.f, hr  = r2.w - r2.y + 1.f;
        const float cxr = 0.5f * (r2.x + r2.z), cyr = 0.5f * (r2.y + r2.w);

        const float f0 = __logf(fabsf((cxn - cxr) / wn) + 0.001f);
        const float f1 = __logf(fabsf((cyn - cyr) / hn) + 0.001f);
        const float f2 = __logf(wn / wr);
        const float f3 = __logf(hn / hr);
        const float fa = (quad & 2) ? f1 : f0;
        const float fb = (quad & 2) ? f3 : f2;

        f32x4 acc = {};
        #pragma unroll
        for (int ks = 0; ks < 2; ++ks) {
            const float feat = ks ? fb : fa;
            f16x8 ef;
            #pragma unroll
            for (int j = 0; j < 8; ++j)
                ef[j] = (_Float16)__sinf(fmaf(feat, fr8[j], phase));
            acc = __builtin_amdgcn_mfma_f32_16x16x32_f16(ef, wgf[ks], acc, 0, 0, 0);
        }

        __half p[4];
        #pragma unroll
        for (int r = 0; r < 4; ++r)
            p[r] = __float2half(fmaxf(acc[r] + bgv, 0.f) + 1e-6f);
        *(uint2*)&AWt[awt_idx(l15, mt0 >> 4, n, quad)] = *(const uint2*)p;
    }
}

// ---------------------------------------------------------------------------
// Wave-autonomous MFMA attention (R4 verbatim). Block = (16-row n-band, g);
// 4 waves each own a 256-m chunk (no barriers in m-loop); LDS combine.
// ---------------------------------------------------------------------------
__global__ __launch_bounds__(256)
void attn_mfma(const __bf16* __restrict__ Qf, const __bf16* __restrict__ Kf,
               const __bf16* __restrict__ Vf, const __half* __restrict__ AWt,
               const float* __restrict__ bv, float* __restrict__ out)
{
    __shared__ __bf16 Ps[4][2][16][72];
    __shared__ float accb[4][64][17];
    __shared__ float lsb[4][16];

    const int tid = threadIdx.x;
    const int w = tid >> 6, lane = tid & 63;
    const int quad = lane >> 4, l15 = lane & 15;
    const int nb = blockIdx.x, n0 = nb * 16, g = blockIdx.y;

    bf16x8 qf[2];
    qf[0] = *(const bf16x8*)&Qf[qkf_idx(g, nb, 0, lane)];
    qf[1] = *(const bf16x8*)&Qf[qkf_idx(g, nb, 1, lane)];

    f32x4 acc[4] = {};
    float llocal = 0.f;

    #pragma unroll
    for (int t64 = 0; t64 < 4; ++t64) {
        const int mt = w * 4 + t64;
        const int buf = t64 & 1;

        f32x4 s[4];
        #pragma unroll
        for (int t = 0; t < 4; ++t) {
            bf16x8 ka0 = *(const bf16x8*)&Kf[qkf_idx(g, mt * 4 + t, 0, lane)];
            bf16x8 ka1 = *(const bf16x8*)&Kf[qkf_idx(g, mt * 4 + t, 1, lane)];
            f32x4 z = {};
            z = __builtin_amdgcn_mfma_f32_16x16x32_bf16(ka0, qf[0], z, 0, 0, 0);
            s[t] = __builtin_amdgcn_mfma_f32_16x16x32_bf16(ka1, qf[1], z, 0, 0, 0);
        }

        #pragma unroll
        for (int t = 0; t < 4; ++t) {
            uint2 au = *(const uint2*)&AWt[awt_idx(g, mt * 4 + t, n0 + l15, quad)];
            const __half* a4 = (const __half*)&au;
            __bf16 pk[4];
            #pragma unroll
            for (int r = 0; r < 4; ++r) {
                const float p = __half2float(a4[r]) * __expf(s[t][r]);
                llocal += p;
                pk[r] = (__bf16)p;
            }
            *(uint2*)&Ps[w][buf][l15][t * 16 + quad * 4] = *(const uint2*)pk;
        }

        #pragma unroll
        for (int mcl = 0; mcl < 2; ++mcl) {
            bf16x8 pbf = *(const bf16x8*)&Ps[w][buf][l15][mcl * 32 + quad * 8];
            #pragma unroll
            for (int ot = 0; ot < 4; ++ot) {
                bf16x8 va = *(const bf16x8*)&Vf[vf_idx(g, ot, mt * 2 + mcl, lane)];
                acc[ot] = __builtin_amdgcn_mfma_f32_16x16x32_bf16(va, pbf, acc[ot], 0, 0, 0);
            }
        }
    }

    llocal += __shfl_xor(llocal, 16, 64);
    llocal += __shfl_xor(llocal, 32, 64);

    #pragma unroll
    for (int ot = 0; ot < 4; ++ot)
        #pragma unroll
        for (int r = 0; r < 4; ++r)
            accb[w][ot * 16 + quad * 4 + r][l15] = acc[ot][r];
    if (quad == 0) lsb[w][l15] = llocal;
    __syncthreads();

    const float lt = lsb[0][l15] + lsb[1][l15] + lsb[2][l15] + lsb[3][l15];
    const float inv = 1.f / lt;
    #pragma unroll
    for (int r = 0; r < 4; ++r) {
        const int o = w * 16 + quad * 4 + r;
        const int ogl = g * 64 + o;
        const float v = accb[0][o][l15] + accb[1][o][l15] +
                        accb[2][o][l15] + accb[3][o][l15];
        out[(size_t)(n0 + l15) * D_ + ogl] = v * inv + bv[ogl];
    }
}

extern "C" void kernel_launch(void* const* d_in, const int* in_sizes, int n_in,
                              void* d_out, int out_size, void* d_ws, size_t ws_size,
                              hipStream_t stream) {
    const float* roi_feat = (const float*)d_in[0];
    const float* ref_feat = (const float*)d_in[1];
    const float* rois1    = (const float*)d_in[2];
    const float* rois2    = (const float*)d_in[3];
    const float* Wq       = (const float*)d_in[4];
    const float* bq       = (const float*)d_in[5];
    const float* Wk       = (const float*)d_in[6];
    const float* bk       = (const float*)d_in[7];
    const float* Wg       = (const float*)d_in[8];
    const float* bg       = (const float*)d_in[9];
    const float* Wv       = (const float*)d_in[10];
    const float* bv       = (const float*)d_in[11];
    float* out = (float*)d_out;

    char* ws = (char*)d_ws;
    __bf16* WqT = (__bf16*)(ws + 0);
    __bf16* WkT = (__bf16*)(ws + (2u << 20));
    __bf16* Wvb = (__bf16*)(ws + (4u << 20));
    __bf16* Qf  = (__bf16*)(ws + (6u << 20));
    __bf16* Kf  = (__bf16*)(ws + (8u << 20));
    __bf16* Vf  = (__bf16*)(ws + (10u << 20));
    __half* AWt = (__half*)(ws + (12u << 20));

    dim3 blk(256);
    prep_weights<<<dim3(16, 16, 3), blk, 0, stream>>>(Wq, Wk, Wv, WqT, WkT, Wvb);
    fused_mid<<<dim3(4288), blk, 0, stream>>>(roi_feat, ref_feat, WqT, WkT, Wvb,
                                              bq, bk, Qf, Kf, Vf,
                                              rois1, rois2, Wg, bg, AWt);
    attn_mfma<<<dim3(64, 16), blk, 0, stream>>>(Qf, Kf, Vf, AWt, bv, out);
}

// Round 11
// 149.349 us; speedup vs baseline: 1.4053x; 1.0278x over previous
//
#include <hip/hip_runtime.h>
#include <hip/hip_fp16.h>
#include <cstddef>

#define N_ 1024
#define M_ 1024
#define D_ 1024
#define G_ 16
#define DG_ 64

typedef __bf16 bf16x8 __attribute__((ext_vector_type(8)));
typedef _Float16 f16x8 __attribute__((ext_vector_type(8)));
typedef float f32x4 __attribute__((ext_vector_type(4)));

// Fragment-major layout helpers (R4/R9, verified passing).
__device__ __forceinline__ size_t qkf_idx(int g, int rb, int ks, int lane) {
    return ((((size_t)(g * 64 + rb)) * 2 + ks) * 64 + lane) * 8;
}
__device__ __forceinline__ size_t vf_idx(int g, int ot, int mc, int lane) {
    return ((((size_t)(g * 4 + ot)) * 32 + mc) * 64 + lane) * 8;
}
__device__ __forceinline__ size_t awt_idx(int g, int mb, int n, int quad) {
    return (((size_t)(g * 64 + mb)) * 1024 + n) * 16 + quad * 4;
}

// ---------------------------------------------------------------------------
// Fused dispatch #1: blocks 0..191 = gemm (128x128 tile, BK=64, fp32 weights
// transpose-cast during LDS staging — no prep dispatch); blocks 192..4287 =
// posbias (MFMA f16, AWt fragment layout). Independent work co-scheduled so
// posbias's VALU work fills the latency-bound gemm blocks' idle pipes.
// ---------------------------------------------------------------------------
__global__ __launch_bounds__(256)
void fused_mid(const float* __restrict__ roi, const float* __restrict__ ref,
               const float* __restrict__ Wq, const float* __restrict__ Wk,
               const float* __restrict__ Wv,
               const float* __restrict__ bq, const float* __restrict__ bk,
               __bf16* __restrict__ Qf, __bf16* __restrict__ Kf,
               __bf16* __restrict__ Vf,
               const float* __restrict__ rois1, const float* __restrict__ rois2,
               const float* __restrict__ Wg, const float* __restrict__ bg,
               __half* __restrict__ AWt)
{
    __shared__ __align__(16) char smem[36864];
    const int b = blockIdx.x;
    const int tid = threadIdx.x;
    const int w = tid >> 6, lane = tid & 63;
    const int quad = lane >> 4, l15 = lane & 15;

    if (b < 192) {
        // ---------------- GEMM branch ----------------
        const int z = b >> 6, t6 = b & 63;
        const float* A = (z == 0) ? roi : ref;
        const float* Wf = (z == 0) ? Wq : (z == 1) ? Wk : Wv;
        const int i0 = (t6 >> 3) * 128, j0 = (t6 & 7) * 128;
        const int iw = (w & 1) * 64, jw = (w >> 1) * 64;

        __bf16(*As)[72] = (__bf16(*)[72])smem;
        __bf16(*Bs)[72] = (__bf16(*)[72])(smem + 18432);

        f32x4 acc[4][4] = {};

        for (int k0 = 0; k0 < D_; k0 += 64) {
            __syncthreads();
            // A: 128 rows x 16 float4 chunks, cast fp32->bf16
            #pragma unroll
            for (int it = 0; it < 8; ++it) {
                const int idx = tid + 256 * it;
                const int row = idx >> 4, c = idx & 15;
                float4 a = *(const float4*)&A[(size_t)(i0 + row) * D_ + k0 + c * 4];
                __bf16 p[4] = {(__bf16)a.x, (__bf16)a.y, (__bf16)a.z, (__bf16)a.w};
                *(uint2*)&As[row][c * 4] = *(const uint2*)p;
            }
            if (z < 2) {
                // B = W^T: transpose-cast during staging.
                // Bs[j][k] = (bf16) W[k0+k][j0+j]. Coalesced dword loads down k.
                #pragma unroll
                for (int it = 0; it < 8; ++it) {
                    const int idx = tid + 256 * it;
                    const int jl = idx & 127;          // j-local (fast: coalesced)
                    const int kc = idx >> 7;           // 0..15 -> k-local 4*kc..
                    const float* src = &Wf[(size_t)(k0 + kc * 4) * D_ + j0 + jl];
                    __bf16 p[4];
                    p[0] = (__bf16)src[0];
                    p[1] = (__bf16)src[D_];
                    p[2] = (__bf16)src[2 * D_];
                    p[3] = (__bf16)src[3 * D_];
                    *(uint2*)&Bs[jl][kc * 4] = *(const uint2*)p;
                }
            } else {
                // Wv already [go][d]: stage with cast, like A.
                #pragma unroll
                for (int it = 0; it < 8; ++it) {
                    const int idx = tid + 256 * it;
                    const int row = idx >> 4, c = idx & 15;
                    float4 a = *(const float4*)&Wf[(size_t)(j0 + row) * D_ + k0 + c * 4];
                    __bf16 p[4] = {(__bf16)a.x, (__bf16)a.y, (__bf16)a.z, (__bf16)a.w};
                    *(uint2*)&Bs[row][c * 4] = *(const uint2*)p;
                }
            }
            __syncthreads();
            #pragma unroll
            for (int ks = 0; ks < 2; ++ks) {
                bf16x8 af[4], bfr[4];
                #pragma unroll
                for (int t = 0; t < 4; ++t) {
                    af[t]  = *(const bf16x8*)&As[iw + t * 16 + l15][ks * 32 + quad * 8];
                    bfr[t] = *(const bf16x8*)&Bs[jw + t * 16 + l15][ks * 32 + quad * 8];
                }
                #pragma unroll
                for (int ti = 0; ti < 4; ++ti)
                    #pragma unroll
                    for (int tj = 0; tj < 4; ++tj)
                        acc[ti][tj] = __builtin_amdgcn_mfma_f32_16x16x32_bf16(
                            af[ti], bfr[tj], acc[ti][tj], 0, 0, 0);
            }
        }

        if (z < 2) {
            const float* bias = (z == 0) ? bq : bk;
            __bf16* dst = (z == 0) ? Qf : Kf;
            const float scale = (z == 0) ? 0.125f : 1.0f;
            #pragma unroll
            for (int ti = 0; ti < 4; ++ti) {
                const int rb = (i0 + iw + ti * 16) >> 4;
                #pragma unroll
                for (int tj = 0; tj < 4; ++tj) {
                    const int go = j0 + jw + tj * 16 + l15;
                    const int g = go >> 6, ks = (go >> 5) & 1;
                    const int lanef = ((go >> 3) & 3) * 16;
                    const int jf = go & 7;
                    const float bb = bias[go];
                    __bf16* base = dst + qkf_idx(g, rb, ks, 0) + jf;
                    #pragma unroll
                    for (int r = 0; r < 4; ++r)
                        base[(size_t)(lanef + quad * 4 + r) * 8] =
                            (__bf16)((acc[ti][tj][r] + bb) * scale);
                }
            }
        } else {
            #pragma unroll
            for (int ti = 0; ti < 4; ++ti) {
                const int mbase = i0 + iw + ti * 16 + quad * 4;
                const int mc = mbase >> 5, quadv = (mbase >> 3) & 3, jb = mbase & 7;
                #pragma unroll
                for (int tj = 0; tj < 4; ++tj) {
                    const int go = j0 + jw + tj * 16 + l15;
                    const int g = go >> 6, ot = (go >> 4) & 3, o15 = go & 15;
                    __bf16 p[4];
                    #pragma unroll
                    for (int r = 0; r < 4; ++r) p[r] = (__bf16)acc[ti][tj][r];
                    *(uint2*)&Vf[vf_idx(g, ot, mc, quadv * 16 + o15) + jb] =
                        *(const uint2*)p;
                }
            }
        }
        return;
    }

    // ---------------- posbias branch (R9 verbatim) ----------------
    const int pb = b - 192;
    const int n = pb >> 2;
    const int m0w = (pb & 3) * 256 + w * 64;

    const float xmin = rois1[n * 4 + 0], ymin = rois1[n * 4 + 1];
    const float xmax = rois1[n * 4 + 2], ymax = rois1[n * 4 + 3];
    const float wn  = xmax - xmin + 1.f, hn  = ymax - ymin + 1.f;
    const float cxn = 0.5f * (xmin + xmax), cyn = 0.5f * (ymin + ymax);

    f16x8 wgf[2];
    #pragma unroll
    for (int ks = 0; ks < 2; ++ks) {
        const float* p = &Wg[l15 * 64 + ks * 32 + quad * 8];
        float4 a = *(const float4*)p;
        float4 bb = *(const float4*)(p + 4);
        wgf[ks][0] = (_Float16)a.x; wgf[ks][1] = (_Float16)a.y;
        wgf[ks][2] = (_Float16)a.z; wgf[ks][3] = (_Float16)a.w;
        wgf[ks][4] = (_Float16)bb.x; wgf[ks][5] = (_Float16)bb.y;
        wgf[ks][6] = (_Float16)bb.z; wgf[ks][7] = (_Float16)bb.w;
    }
    const float bgv = bg[l15];

    const float fr8[8] = {100.0f, 42.16965f, 17.782794f, 7.4989421f,
                          3.1622777f, 1.3335214f, 0.56234133f, 0.23713737f};
    const float phase = (quad & 1) ? 1.5707963267948966f : 0.f;

    #pragma unroll
    for (int ti = 0; ti < 4; ++ti) {
        const int mt0 = m0w + ti * 16;
        const int m = mt0 + l15;
        float4 r2 = *(const float4*)&rois2[m * 4];
        const float wr  = r2.z - r2.x + 1.f, hr  = r2.w - r2.y + 1.f;
        const float cxr = 0.5f * (r2.x + r2.z), cyr = 0.5f * (r2.y + r2.w);

        const float f0 = __logf(fabsf((cxn - cxr) / wn) + 0.001f);
        const float f1 = __logf(fabsf((cyn - cyr) / hn) + 0.001f);
        const float f2 = __logf(wn / wr);
        const float f3 = __logf(hn / hr);
        const float fa = (quad & 2) ? f1 : f0;
        const float fb = (quad & 2) ? f3 : f2;

        f32x4 acc = {};
        #pragma unroll
        for (int ks = 0; ks < 2; ++ks) {
            const float feat = ks ? fb : fa;
            f16x8 ef;
            #pragma unroll
            for (int j = 0; j < 8; ++j)
                ef[j] = (_Float16)__sinf(fmaf(feat, fr8[j], phase));
            acc = __builtin_amdgcn_mfma_f32_16x16x32_f16(ef, wgf[ks], acc, 0, 0, 0);
        }

        __half p[4];
        #pragma unroll
        for (int r = 0; r < 4; ++r)
            p[r] = __float2half(fmaxf(acc[r] + bgv, 0.f) + 1e-6f);
        *(uint2*)&AWt[awt_idx(l15, mt0 >> 4, n, quad)] = *(const uint2*)p;
    }
}

// ---------------------------------------------------------------------------
// Wave-autonomous MFMA attention (R4/R9 verbatim). Block = (16-n band, g);
// 4 waves each own a 256-m chunk (no barriers in m-loop); LDS combine.
// ---------------------------------------------------------------------------
__global__ __launch_bounds__(256)
void attn_mfma(const __bf16* __restrict__ Qf, const __bf16* __restrict__ Kf,
               const __bf16* __restrict__ Vf, const __half* __restrict__ AWt,
               const float* __restrict__ bv, float* __restrict__ out)
{
    __shared__ __bf16 Ps[4][2][16][72];
    __shared__ float accb[4][64][17];
    __shared__ float lsb[4][16];

    const int tid = threadIdx.x;
    const int w = tid >> 6, lane = tid & 63;
    const int quad = lane >> 4, l15 = lane & 15;
    const int nb = blockIdx.x, n0 = nb * 16, g = blockIdx.y;

    bf16x8 qf[2];
    qf[0] = *(const bf16x8*)&Qf[qkf_idx(g, nb, 0, lane)];
    qf[1] = *(const bf16x8*)&Qf[qkf_idx(g, nb, 1, lane)];

    f32x4 acc[4] = {};
    float llocal = 0.f;

    #pragma unroll
    for (int t64 = 0; t64 < 4; ++t64) {
        const int mt = w * 4 + t64;
        const int buf = t64 & 1;

        f32x4 s[4];
        #pragma unroll
        for (int t = 0; t < 4; ++t) {
            bf16x8 ka0 = *(const bf16x8*)&Kf[qkf_idx(g, mt * 4 + t, 0, lane)];
            bf16x8 ka1 = *(const bf16x8*)&Kf[qkf_idx(g, mt * 4 + t, 1, lane)];
            f32x4 z = {};
            z = __builtin_amdgcn_mfma_f32_16x16x32_bf16(ka0, qf[0], z, 0, 0, 0);
            s[t] = __builtin_amdgcn_mfma_f32_16x16x32_bf16(ka1, qf[1], z, 0, 0, 0);
        }

        #pragma unroll
        for (int t = 0; t < 4; ++t) {
            uint2 au = *(const uint2*)&AWt[awt_idx(g, mt * 4 + t, n0 + l15, quad)];
            const __half* a4 = (const __half*)&au;
            __bf16 pk[4];
            #pragma unroll
            for (int r = 0; r < 4; ++r) {
                const float p = __half2float(a4[r]) * __expf(s[t][r]);
                llocal += p;
                pk[r] = (__bf16)p;
            }
            *(uint2*)&Ps[w][buf][l15][t * 16 + quad * 4] = *(const uint2*)pk;
        }

        #pragma unroll
        for (int mcl = 0; mcl < 2; ++mcl) {
            bf16x8 pbf = *(const bf16x8*)&Ps[w][buf][l15][mcl * 32 + quad * 8];
            #pragma unroll
            for (int ot = 0; ot < 4; ++ot) {
                bf16x8 va = *(const bf16x8*)&Vf[vf_idx(g, ot, mt * 2 + mcl, lane)];
                acc[ot] = __builtin_amdgcn_mfma_f32_16x16x32_bf16(va, pbf, acc[ot], 0, 0, 0);
            }
        }
    }

    llocal += __shfl_xor(llocal, 16, 64);
    llocal += __shfl_xor(llocal, 32, 64);

    #pragma unroll
    for (int ot = 0; ot < 4; ++ot)
        #pragma unroll
        for (int r = 0; r < 4; ++r)
            accb[w][ot * 16 + quad * 4 + r][l15] = acc[ot][r];
    if (quad == 0) lsb[w][l15] = llocal;
    __syncthreads();

    const float lt = lsb[0][l15] + lsb[1][l15] + lsb[2][l15] + lsb[3][l15];
    const float inv = 1.f / lt;
    #pragma unroll
    for (int r = 0; r < 4; ++r) {
        const int o = w * 16 + quad * 4 + r;
        const int ogl = g * 64 + o;
        const float v = accb[0][o][l15] + accb[1][o][l15] +
                        accb[2][o][l15] + accb[3][o][l15];
        out[(size_t)(n0 + l15) * D_ + ogl] = v * inv + bv[ogl];
    }
}

extern "C" void kernel_launch(void* const* d_in, const int* in_sizes, int n_in,
                              void* d_out, int out_size, void* d_ws, size_t ws_size,
                              hipStream_t stream) {
    const float* roi_feat = (const float*)d_in[0];
    const float* ref_feat = (const float*)d_in[1];
    const float* rois1    = (const float*)d_in[2];
    const float* rois2    = (const float*)d_in[3];
    const float* Wq       = (const float*)d_in[4];
    const float* bq       = (const float*)d_in[5];
    const float* Wk       = (const float*)d_in[6];
    const float* bk       = (const float*)d_in[7];
    const float* Wg       = (const float*)d_in[8];
    const float* bg       = (const float*)d_in[9];
    const float* Wv       = (const float*)d_in[10];
    const float* bv       = (const float*)d_in[11];
    float* out = (float*)d_out;

    // ws (bytes): Qf 0-2M | Kf 2-4M | Vf 4-6M | AWt 6-38M
    char* ws = (char*)d_ws;
    __bf16* Qf  = (__bf16*)(ws + 0);
    __bf16* Kf  = (__bf16*)(ws + (2u << 20));
    __bf16* Vf  = (__bf16*)(ws + (4u << 20));
    __half* AWt = (__half*)(ws + (6u << 20));

    dim3 blk(256);
    fused_mid<<<dim3(4288), blk, 0, stream>>>(roi_feat, ref_feat, Wq, Wk, Wv,
                                              bq, bk, Qf, Kf, Vf,
                                              rois1, rois2, Wg, bg, AWt);
    attn_mfma<<<dim3(64, 16), blk, 0, stream>>>(Qf, Kf, Vf, AWt, bv, out);
}